// Round 4
// baseline (278.227 us; speedup 1.0000x reference)
//
#include <hip/hip_runtime.h>

#define T_TOK 8192
#define D_IN  4096
#define D_OUT 4096

typedef _Float16 h2 __attribute__((ext_vector_type(2)));
typedef _Float16 h4 __attribute__((ext_vector_type(4)));
typedef _Float16 h8 __attribute__((ext_vector_type(8)));
typedef float    f4v __attribute__((ext_vector_type(4)));

__device__ __forceinline__ h2 pkrtz(float a, float b) {
    auto r = __builtin_amdgcn_cvt_pkrtz(a, b);
    h2 o; __builtin_memcpy(&o, &r, 4); return o;
}
__device__ __forceinline__ h8 cvt8(float4 f0, float4 f1) {
    h2 p0 = pkrtz(f0.x, f0.y), p1 = pkrtz(f0.z, f0.w);
    h2 p2 = pkrtz(f1.x, f1.y), p3 = pkrtz(f1.z, f1.w);
    return (h8){p0.x, p0.y, p1.x, p1.y, p2.x, p2.y, p3.x, p3.y};
}

// async 16B global->LDS (hardware DMA: wave-uniform LDS base + lane*16)
__device__ __forceinline__ void gl_lds16(const void* g, void* l) {
    __builtin_amdgcn_global_load_lds(
        (const __attribute__((address_space(1))) unsigned int*)g,
        (__attribute__((address_space(3))) unsigned int*)l, 16, 0, 0);
}

// MFMA 16x16x32 f16 layouts (verified m89/m91/m120):
//   A-frag: lane holds A[m=lane&15][k=(lane>>4)*8+j], j=0..7 (one 16B h8)
//   B-frag: lane holds B[k=(lane>>4)*8+j][n=lane&15]
//   C/D:    row=(lane>>4)*4+reg, col=lane&15
// All LDS tiles are stored as 1024B "planes": lane l's h8 at plane + l*16.
// Wave ds_read_b128 is then contiguous 1024B -> zero bank conflicts.

// ---- prep: Wa->WaB planes (bid<256), Wb->WbB planes (bid<384), aux ----------
__global__ __launch_bounds__(256)
void prep(const float* __restrict__ Wa, const float* __restrict__ Wb,
          const float* __restrict__ la, const float* __restrict__ lb,
          _Float16* __restrict__ WaB, _Float16* __restrict__ WbB,
          double* __restrict__ pax) {
    const int bid = blockIdx.x, tx = threadIdx.x;
    __shared__ double red[4][16];
    if (bid < 256) {
        // Wa [er=64][k=4096] f32. Element (er,k) -> chunk it=k>>7, plane
        // p=ks*4+g (ks=(k>>5)&3, g=er>>4), lane kf*16+mr (kf=(k>>3)&3,
        // mr=er&15), byte j=k&7. h-off = it*8192 + p*512 + (kf*16+mr)*8 + j
        int gid = bid * 256 + tx;                // 0..65535
        int er = gid >> 10, k0 = (gid & 1023) * 4;
        float4 v = ((const float4*)Wa)[gid];
        h2 p0 = pkrtz(v.x, v.y), p1 = pkrtz(v.z, v.w);
        h4 o = { p0.x, p0.y, p1.x, p1.y };
        int it = k0 >> 7, ks = (k0 >> 5) & 3, kf = (k0 >> 3) & 3;
        int g = er >> 4, mr = er & 15;
        *(h4*)(WaB + it * 8192 + (ks * 4 + g) * 512 + (kf * 16 + mr) * 8
               + (k0 & 7)) = o;
    } else if (bid < 384) {
        // Wb [e][o][r] f32, k=e*8+r, n=o. -> chunk ch=o>>7, plane p=ks*8+wv
        // (ks=e>>2, wv=(o>>4)&7), lane kf*16+mr (kf=e&3, mr=o&15), byte j=r.
        int gid = (bid - 256) * 256 + tx;        // 0..32767
        int e = gid >> 12, o = gid & 4095;
        const float4* p = (const float4*)(Wb + ((size_t)e * 4096 + o) * 8);
        h8 v = cvt8(p[0], p[1]);
        int ch = o >> 7, wv = (o >> 4) & 7, mr = o & 15;
        *(h8*)(WbB + (size_t)ch * 8192 + ((e >> 2) * 8 + wv) * 512
               + ((e & 3) * 16 + mr) * 8) = v;
    } else {
        // aux_partial: 32 blocks, per-token full softmax partial sums (f64)
        const int ab = bid - 384;
        const int t = ab * 256 + tx;
        double loc[16];
        {
            float l[8];
#pragma unroll
            for (int i = 0; i < 8; ++i) l[i] = la[(size_t)t * 8 + i];
            float m = l[0];
#pragma unroll
            for (int i = 1; i < 8; ++i) m = fmaxf(m, l[i]);
            float s = 0.f, e[8];
#pragma unroll
            for (int i = 0; i < 8; ++i) { e[i] = __expf(l[i] - m); s += e[i]; }
#pragma unroll
            for (int i = 0; i < 8; ++i) loc[i] = (double)(e[i] / s);
        }
        {
            float l[8];
#pragma unroll
            for (int i = 0; i < 8; ++i) l[i] = lb[(size_t)t * 8 + i];
            float m = l[0];
#pragma unroll
            for (int i = 1; i < 8; ++i) m = fmaxf(m, l[i]);
            float s = 0.f, e[8];
#pragma unroll
            for (int i = 0; i < 8; ++i) { e[i] = __expf(l[i] - m); s += e[i]; }
#pragma unroll
            for (int i = 0; i < 8; ++i) loc[8 + i] = (double)(e[i] / s);
        }
        const int lane = tx & 63, wid = tx >> 6;
#pragma unroll
        for (int v = 0; v < 16; ++v) {
            double s = loc[v];
#pragma unroll
            for (int off = 32; off > 0; off >>= 1) s += __shfl_down(s, off, 64);
            if (lane == 0) red[wid][v] = s;
        }
        __syncthreads();
        if (tx < 16)
            pax[ab * 16 + tx] = red[0][tx] + red[1][tx] + red[2][tx] + red[3][tx];
    }
}

// ---- fused: GEMM1 (x@WaT) + routing + GEMM2 (Mb@WbF) in one pass ------------
// 512 blocks x 512 thr (8 waves); 16 tokens/block; 16 waves/CU.
// Phase 1: 8 waves = 4 er-groups x 2 K-halves.  Phase 3: 8 waves = 8 col-slices.
// All staging via global_load_lds into read-order planes (conflict-free).
__global__ __launch_bounds__(512, 4)
void fused(const float* __restrict__ x, const _Float16* __restrict__ WaB,
           const _Float16* __restrict__ WbB, const float* __restrict__ la,
           const float* __restrict__ lb, float* __restrict__ out,
           const double* __restrict__ pax) {
    // S layout (bytes):
    //  [0,16384)      xb dbuf   2 x 8 planes  (phase 1 x tile)
    //  [16384,49152)  wab dbuf  2 x 16 planes (phase 1 Wa tile)
    //  phase 3 overlay: [0,32768) wbb dbuf 2 x 16 planes
    //  [32768,41216)  pL[2][16][66] f32   (overlays dead wab[1])
    //  [41216,43264)  MbL 1024 h16        (overlays dead wab[1])
    __shared__ char S[49152];
    __shared__ float sW0[16], sW1[16], sCb[16][8];
    __shared__ int   sE0[16], sE1[16];
    __shared__ double sl[16];

    const int tx = threadIdx.x, l = tx & 63, w = tx >> 6;
    const int mr = l & 15, kf = l >> 4;
    const int m0 = blockIdx.x * 16;
    const int g  = w & 3;              // er-group   (phase 1)
    const int kh = w >> 2;             // K-half     (phase 1)
    const int er1 = g * 16 + mr;
    float* pLp = (float*)(S + 32768);  // [kh][tok][er] stride 66
    _Float16* MbLp = (_Float16*)(S + 41216);

    // ================= phase 1: part[16x64] = x[16x4096] @ WaT ===============
    f4v acc = (f4v){0.f, 0.f, 0.f, 0.f};

    // staging: 24 planes/iter (8 x-planes + 16 wa-planes), 3 per wave.
    // x-plane p (ks=p>>1, hf=p&1): lane (kf,mr) <- x[m0+mr][it*128+ks*32+kf*8+hf*4 ..+4]
#define STAGE1(IT, BUF) do {                                                   \
    _Pragma("unroll") for (int i_ = 0; i_ < 3; ++i_) {                         \
        int p_ = w * 3 + i_;                                                   \
        if (p_ < 8) {                                                          \
            const char* src_ = (const char*)x + (size_t)(m0 + mr) * 16384      \
                + (size_t)(IT) * 512 + (p_ >> 1) * 128 + kf * 32 + (p_ & 1) * 16; \
            gl_lds16(src_, S + (BUF) * 8192 + p_ * 1024);                      \
        } else {                                                               \
            int q_ = p_ - 8;                                                   \
            const char* src_ = (const char*)WaB + (size_t)(IT) * 16384         \
                + q_ * 1024 + l * 16;                                          \
            gl_lds16(src_, S + 16384 + (BUF) * 16384 + q_ * 1024);             \
        }                                                                      \
    }                                                                          \
  } while (0)

#define CMP1(BUF) do {                                                         \
    _Pragma("unroll") for (int i_ = 0; i_ < 2; ++i_) {                         \
        int ks_ = kh * 2 + i_;                                                 \
        float4 f0_ = *(const float4*)(S + (BUF) * 8192 + (ks_ * 2) * 1024 + l * 16);     \
        float4 f1_ = *(const float4*)(S + (BUF) * 8192 + (ks_ * 2 + 1) * 1024 + l * 16); \
        h8 a_ = cvt8(f0_, f1_);                                                \
        h8 b_ = *(const h8*)(S + 16384 + (BUF) * 16384                         \
                             + (ks_ * 4 + g) * 1024 + l * 16);                 \
        acc = __builtin_amdgcn_mfma_f32_16x16x32_f16(a_, b_, acc, 0, 0, 0);    \
    }                                                                          \
  } while (0)

    STAGE1(0, 0);
    __syncthreads();
#pragma unroll 1
    for (int it = 0; it < 32; ++it) {
        if (it < 31) STAGE1(it + 1, (it & 1) ^ 1);
        CMP1(it & 1);
        __syncthreads();
    }
#undef STAGE1
#undef CMP1

    // ================= phase 2: routing -> Mb fragment panel =================
    // C/D: token row = kf*4+r, er col = er1. pL overlays dead wab[1].
#pragma unroll
    for (int r = 0; r < 4; ++r) pLp[kh * 1056 + (kf * 4 + r) * 66 + er1] = acc[r];
    __syncthreads();

    if (tx < 16) {
        const int t = tx;
        float lg[8];
#pragma unroll
        for (int i = 0; i < 8; ++i) lg[i] = la[(size_t)(m0 + t) * 8 + i];
        int e0 = 0; float b0 = lg[0];
#pragma unroll
        for (int i = 1; i < 8; ++i) if (lg[i] > b0) { b0 = lg[i]; e0 = i; }
        int e1 = -1; float b1 = -1e30f;
#pragma unroll
        for (int i = 0; i < 8; ++i) if (i != e0 && lg[i] > b1) { b1 = lg[i]; e1 = i; }
        float w1 = __expf(b1 - b0), s = 1.f + w1;
        sW0[t] = 1.f / s; sW1[t] = w1 / s; sE0[t] = e0; sE1[t] = e1;

#pragma unroll
        for (int i = 0; i < 8; ++i) lg[i] = lb[(size_t)(m0 + t) * 8 + i];
        int f0 = 0; float c0 = lg[0];
#pragma unroll
        for (int i = 1; i < 8; ++i) if (lg[i] > c0) { c0 = lg[i]; f0 = i; }
        int f1 = -1; float c1 = -1e30f;
#pragma unroll
        for (int i = 0; i < 8; ++i) if (i != f0 && lg[i] > c1) { c1 = lg[i]; f1 = i; }
        float wb1 = __expf(c1 - c0), sb = 1.f + wb1;
        float wb0s = 2.f / sb, wb1s = 2.f * wb1 / sb;   // SCALING=2 folded in
#pragma unroll
        for (int e = 0; e < 8; ++e)
            sCb[t][e] = (e == f0) ? wb0s : (e == f1) ? wb1s : 0.f;
    }
    __syncthreads();

    if (tx < 256) {
        const int t = tx >> 4, gg = tx & 15;
        const float w0 = sW0[t], w1 = sW1[t];
        const int e0 = sE0[t], e1 = sE1[t];
        const float cb = sCb[t][gg >> 1];
        h4 o;
#pragma unroll
        for (int j = 0; j < 4; ++j) {
            int r = (gg * 4 + j) & 7;
            float mid = w0 * (pLp[t * 66 + e0 * 8 + r] + pLp[1056 + t * 66 + e0 * 8 + r])
                      + w1 * (pLp[t * 66 + e1 * 8 + r] + pLp[1056 + t * 66 + e1 * 8 + r]);
            o[j] = (_Float16)(cb * mid);
        }
        *(h4*)(MbLp + ((gg >> 1) * 16 + t) * 8 + (gg & 1) * 4) = o;
    }
    __syncthreads();

    // ================= phase 3: out[16x4096] = Mb[16x64] @ WbF ===============
    // A-frags in regs; WbB per 128-col chunk: 16 planes (p=ks*8+wave), dbuf
    // at S[0,32768) (xb+wab[0] dead). Wave w covers cols ch*128+w*16+[0,16).
    h8 a30 = *(const h8*)(MbLp + ((0 * 4 + kf) * 16 + mr) * 8);
    h8 a31 = *(const h8*)(MbLp + ((1 * 4 + kf) * 16 + mr) * 8);
    float* outp = out + (size_t)(m0 + kf * 4) * D_OUT;

#define STAGE3(CH, BUF) do {                                                   \
    _Pragma("unroll") for (int i_ = 0; i_ < 2; ++i_) {                         \
        int p_ = w * 2 + i_;                                                   \
        const char* src_ = (const char*)WbB + (size_t)(CH) * 16384             \
            + p_ * 1024 + l * 16;                                              \
        gl_lds16(src_, S + (BUF) * 16384 + p_ * 1024);                         \
    }                                                                          \
  } while (0)

#define CMP3(BUF, CH) do {                                                     \
    f4v o0 = (f4v){0.f,0.f,0.f,0.f};                                           \
    h8 b0_ = *(const h8*)(S + (BUF) * 16384 + (0 * 8 + w) * 1024 + l * 16);    \
    h8 b1_ = *(const h8*)(S + (BUF) * 16384 + (1 * 8 + w) * 1024 + l * 16);    \
    o0 = __builtin_amdgcn_mfma_f32_16x16x32_f16(a30, b0_, o0, 0, 0, 0);        \
    o0 = __builtin_amdgcn_mfma_f32_16x16x32_f16(a31, b1_, o0, 0, 0, 0);        \
    int n0_ = (CH) * 128 + w * 16 + mr;                                        \
    _Pragma("unroll") for (int r_ = 0; r_ < 4; ++r_)                           \
        outp[(size_t)r_ * D_OUT + n0_] = o0[r_];                               \
  } while (0)

    STAGE3(0, 0);
    __syncthreads();
#pragma unroll 1
    for (int c = 0; c < 32; ++c) {
        if (c < 31) STAGE3(c + 1, (c & 1) ^ 1);
        CMP3(c & 1, c);
        __syncthreads();
    }
#undef STAGE3
#undef CMP3

    // ================= aux_final (block 0 only) ==============================
    if (blockIdx.x == 0) {
        if (tx < 16) {
            double s = 0.0;
#pragma unroll
            for (int b = 0; b < 32; ++b) s += pax[b * 16 + tx];
            sl[tx] = s;
        }
        __syncthreads();
        if (tx == 0) {
            double pa[8], pb[8], ma = 0.0, mb = 0.0;
            for (int e = 0; e < 8; ++e) { pa[e] = sl[e] / 8192.0;     ma += pa[e] / 8.0; }
            for (int e = 0; e < 8; ++e) { pb[e] = sl[8 + e] / 8192.0; mb += pb[e] / 8.0; }
            double va = 0.0, vb = 0.0;
            for (int e = 0; e < 8; ++e) { double d = pa[e] - ma; va += d * d; }
            for (int e = 0; e < 8; ++e) { double d = pb[e] - mb; vb += d * d; }
            out[(size_t)T_TOK * D_OUT + 0] = (float)(8.0 * va / 7.0);
            out[(size_t)T_TOK * D_OUT + 1] = (float)(8.0 * vb / 7.0);
        }
    }
}

extern "C" void kernel_launch(void* const* d_in, const int* in_sizes, int n_in,
                              void* d_out, int out_size, void* d_ws, size_t ws_size,
                              hipStream_t stream) {
    const float* x  = (const float*)d_in[0];
    const float* la = (const float*)d_in[1];
    const float* lb = (const float*)d_in[2];
    const float* Wa = (const float*)d_in[3];
    const float* Wb = (const float*)d_in[4];
    float* out = (float*)d_out;

    char* ws = (char*)d_ws;
    _Float16* WaB = (_Float16*)ws;                 // 512 KB
    _Float16* WbB = (_Float16*)(ws + 524288);      // 512 KB
    double*   pax = (double*)(ws + 1048576);       // 4 KB

    prep<<<416, 256, 0, stream>>>(Wa, Wb, la, lb, WaB, WbB, pax);
    fused<<<512, 512, 0, stream>>>(x, WaB, WbB, la, lb, out, pax);
}

// Round 5
// 271.026 us; speedup vs baseline: 1.0266x; 1.0266x over previous
//
#include <hip/hip_runtime.h>

#define T_TOK 8192
#define D_IN  4096
#define D_OUT 4096

typedef _Float16 h2 __attribute__((ext_vector_type(2)));
typedef _Float16 h4 __attribute__((ext_vector_type(4)));
typedef _Float16 h8 __attribute__((ext_vector_type(8)));
typedef float    f4v __attribute__((ext_vector_type(4)));

__device__ __forceinline__ h2 pkrtz(float a, float b) {
    auto r = __builtin_amdgcn_cvt_pkrtz(a, b);
    h2 o; __builtin_memcpy(&o, &r, 4); return o;
}
__device__ __forceinline__ h8 cvt8(float4 f0, float4 f1) {
    h2 p0 = pkrtz(f0.x, f0.y), p1 = pkrtz(f0.z, f0.w);
    h2 p2 = pkrtz(f1.x, f1.y), p3 = pkrtz(f1.z, f1.w);
    return (h8){p0.x, p0.y, p1.x, p1.y, p2.x, p2.y, p3.x, p3.y};
}
__device__ __forceinline__ h8 as_h8(uint4 u) { h8 b; __builtin_memcpy(&b, &u, 16); return b; }

// async 16B global->LDS (hardware DMA: wave-uniform LDS base + lane*16)
__device__ __forceinline__ void gl_lds16(const void* g, void* l) {
    __builtin_amdgcn_global_load_lds(
        (const __attribute__((address_space(1))) unsigned int*)g,
        (__attribute__((address_space(3))) unsigned int*)l, 16, 0, 0);
}

// MFMA 16x16x32 f16 layouts (verified m89/m91/m120):
//   A-frag: lane holds A[m=lane&15][k=(lane>>4)*8+j], j=0..7 (one 16B h8)
//   B-frag: lane holds B[k=(lane>>4)*8+j][n=lane&15]
//   C/D:    row=(lane>>4)*4+reg, col=lane&15
// All LDS/global tiles are stored as 1024B "planes": lane l's h8 at plane+l*16.
// Wave-wide b128 access is then contiguous 1024B -> zero bank conflicts.

// ---- prep: Wa->WaB planes (bid<256), Wb->WbB planes (bid<384), aux ----------
__global__ __launch_bounds__(256)
void prep(const float* __restrict__ Wa, const float* __restrict__ Wb,
          const float* __restrict__ la, const float* __restrict__ lb,
          _Float16* __restrict__ WaB, _Float16* __restrict__ WbB,
          double* __restrict__ pax) {
    const int bid = blockIdx.x, tx = threadIdx.x;
    __shared__ double red[4][16];
    if (bid < 256) {
        // Wa [er=64][k=4096] f32 -> chunk it=k>>7, plane p=ks*4+g, lane kf*16+mr
        int gid = bid * 256 + tx;                // 0..65535
        int er = gid >> 10, k0 = (gid & 1023) * 4;
        float4 v = ((const float4*)Wa)[gid];
        h2 p0 = pkrtz(v.x, v.y), p1 = pkrtz(v.z, v.w);
        h4 o = { p0.x, p0.y, p1.x, p1.y };
        int it = k0 >> 7, ks = (k0 >> 5) & 3, kf = (k0 >> 3) & 3;
        int g = er >> 4, mr = er & 15;
        *(h4*)(WaB + it * 8192 + (ks * 4 + g) * 512 + (kf * 16 + mr) * 8
               + (k0 & 7)) = o;
    } else if (bid < 384) {
        // Wb [e][o][r] f32, k=e*8+r, n=o -> chunk ch=o>>7, plane p=(e>>2)*8+wv,
        // lane (e&3)*16+mr (wv=(o>>4)&7, mr=o&15), byte j=r.
        int gid = (bid - 256) * 256 + tx;        // 0..32767
        int e = gid >> 12, o = gid & 4095;
        const float4* p = (const float4*)(Wb + ((size_t)e * 4096 + o) * 8);
        h8 v = cvt8(p[0], p[1]);
        int ch = o >> 7, wv = (o >> 4) & 7, mr = o & 15;
        *(h8*)(WbB + (size_t)ch * 8192 + ((e >> 2) * 8 + wv) * 512
               + ((e & 3) * 16 + mr) * 8) = v;
    } else {
        // aux_partial: 32 blocks, per-token full softmax partial sums (f64)
        const int ab = bid - 384;
        const int t = ab * 256 + tx;
        double loc[16];
        {
            float l[8];
#pragma unroll
            for (int i = 0; i < 8; ++i) l[i] = la[(size_t)t * 8 + i];
            float m = l[0];
#pragma unroll
            for (int i = 1; i < 8; ++i) m = fmaxf(m, l[i]);
            float s = 0.f, e[8];
#pragma unroll
            for (int i = 0; i < 8; ++i) { e[i] = __expf(l[i] - m); s += e[i]; }
#pragma unroll
            for (int i = 0; i < 8; ++i) loc[i] = (double)(e[i] / s);
        }
        {
            float l[8];
#pragma unroll
            for (int i = 0; i < 8; ++i) l[i] = lb[(size_t)t * 8 + i];
            float m = l[0];
#pragma unroll
            for (int i = 1; i < 8; ++i) m = fmaxf(m, l[i]);
            float s = 0.f, e[8];
#pragma unroll
            for (int i = 0; i < 8; ++i) { e[i] = __expf(l[i] - m); s += e[i]; }
#pragma unroll
            for (int i = 0; i < 8; ++i) loc[8 + i] = (double)(e[i] / s);
        }
        const int lane = tx & 63, wid = tx >> 6;
#pragma unroll
        for (int v = 0; v < 16; ++v) {
            double s = loc[v];
#pragma unroll
            for (int off = 32; off > 0; off >>= 1) s += __shfl_down(s, off, 64);
            if (lane == 0) red[wid][v] = s;
        }
        __syncthreads();
        if (tx < 16)
            pax[ab * 16 + tx] = red[0][tx] + red[1][tx] + red[2][tx] + red[3][tx];
    }
}

// ---- fused: GEMM1 (x@WaT) + routing + GEMM2 (Mb@WbF) in one pass ------------
// 512 blocks x 512 thr (8 waves); 16 tokens/block; 2 blocks/CU (LDS-capped).
// Phase 1: 3-buffer global_load_lds pipeline, counted vmcnt(3) (T4), raw
//          s_barrier (no drain). Pure DMA vmcnt stream -> exact counting.
// Phase 3: barrier-free; wave-private B planes read direct from L2-resident
//          WbB into registers (LDS staging was zero-sharing overhead).
__global__ __launch_bounds__(512, 4)
void fused(const float* __restrict__ x, const _Float16* __restrict__ WaB,
           const _Float16* __restrict__ WbB, const float* __restrict__ la,
           const float* __restrict__ lb, float* __restrict__ out,
           const double* __restrict__ pax) {
    // S: 3 staging buffers x 24576B  (x planes 8KB @+0, Wa planes 16KB @+8192)
    //    phase-2 overlay into dead buf0: pL f32[2][16][66] @+0, MbL @+8448
    __shared__ char S[73728];
    __shared__ float sW0[16], sW1[16], sCb[16][8];
    __shared__ int   sE0[16], sE1[16];
    __shared__ double sl[16];

    const int tx = threadIdx.x, l = tx & 63, w = tx >> 6;
    const int mr = l & 15, kf = l >> 4;
    const int m0 = blockIdx.x * 16;
    const int g  = w & 3;              // er-group   (phase 1)
    const int kh = w >> 2;             // K-half     (phase 1)
    const int er1 = g * 16 + mr;
    float* pLp = (float*)S;            // [kh][tok][er] stride 66 (overlay)
    _Float16* MbLp = (_Float16*)(S + 8448);

    // ================= phase 1: part[16x64] = x[16x4096] @ WaT ===============
    f4v acc = (f4v){0.f, 0.f, 0.f, 0.f};

    // 24 planes/iter (8 x + 16 wa), 3 per wave -> exactly 3 DMAs/lane/iter.
#define STAGE1(IT, BUF) do {                                                   \
    _Pragma("unroll") for (int i_ = 0; i_ < 3; ++i_) {                         \
        int p_ = w * 3 + i_;                                                   \
        if (p_ < 8) {                                                          \
            const char* src_ = (const char*)x + (size_t)(m0 + mr) * 16384      \
                + (size_t)(IT) * 512 + (p_ >> 1) * 128 + kf * 32 + (p_ & 1) * 16; \
            gl_lds16(src_, S + (BUF) * 24576 + p_ * 1024);                     \
        } else {                                                               \
            int q_ = p_ - 8;                                                   \
            const char* src_ = (const char*)WaB + (size_t)(IT) * 16384         \
                + q_ * 1024 + l * 16;                                          \
            gl_lds16(src_, S + (BUF) * 24576 + 8192 + q_ * 1024);              \
        }                                                                      \
    }                                                                          \
  } while (0)

#define CMP1(BUF) do {                                                         \
    _Pragma("unroll") for (int i_ = 0; i_ < 2; ++i_) {                         \
        int ks_ = kh * 2 + i_;                                                 \
        float4 f0_ = *(const float4*)(S + (BUF) * 24576 + (ks_ * 2) * 1024 + l * 16);     \
        float4 f1_ = *(const float4*)(S + (BUF) * 24576 + (ks_ * 2 + 1) * 1024 + l * 16); \
        h8 a_ = cvt8(f0_, f1_);                                                \
        h8 b_ = *(const h8*)(S + (BUF) * 24576 + 8192                          \
                             + (ks_ * 4 + g) * 1024 + l * 16);                 \
        acc = __builtin_amdgcn_mfma_f32_16x16x32_f16(a_, b_, acc, 0, 0, 0);    \
    }                                                                          \
  } while (0)

    STAGE1(0, 0);
    STAGE1(1, 1);
    {
        int bc = 0;                    // buffer of iter it  (it % 3)
        int bs = 2;                    // buffer of iter it+2
#pragma unroll 1
        for (int it = 0; it < 31; ++it) {
            asm volatile("s_waitcnt vmcnt(3)" ::: "memory");  // iter-it DMAs done
            __builtin_amdgcn_s_barrier();                     // raw: no drain
            if (it < 30) STAGE1(it + 2, bs);
            CMP1(bc);
            bc = (bc == 2) ? 0 : bc + 1;
            bs = (bs == 2) ? 0 : bs + 1;
        }
        asm volatile("s_waitcnt vmcnt(0)" ::: "memory");      // last iter drain
        __builtin_amdgcn_s_barrier();
        CMP1(1);                                              // 31 % 3 == 1
    }
#undef STAGE1
#undef CMP1

    // ================= phase 2: routing -> Mb fragment panel =================
    // pL overlays buf0 (dead: all waves past barrier after last buf0 read).
#pragma unroll
    for (int r = 0; r < 4; ++r) pLp[kh * 1056 + (kf * 4 + r) * 66 + er1] = acc[r];
    __syncthreads();

    if (tx < 16) {
        const int t = tx;
        float lg[8];
#pragma unroll
        for (int i = 0; i < 8; ++i) lg[i] = la[(size_t)(m0 + t) * 8 + i];
        int e0 = 0; float b0 = lg[0];
#pragma unroll
        for (int i = 1; i < 8; ++i) if (lg[i] > b0) { b0 = lg[i]; e0 = i; }
        int e1 = -1; float b1 = -1e30f;
#pragma unroll
        for (int i = 0; i < 8; ++i) if (i != e0 && lg[i] > b1) { b1 = lg[i]; e1 = i; }
        float w1 = __expf(b1 - b0), s = 1.f + w1;
        sW0[t] = 1.f / s; sW1[t] = w1 / s; sE0[t] = e0; sE1[t] = e1;

#pragma unroll
        for (int i = 0; i < 8; ++i) lg[i] = lb[(size_t)(m0 + t) * 8 + i];
        int f0 = 0; float c0 = lg[0];
#pragma unroll
        for (int i = 1; i < 8; ++i) if (lg[i] > c0) { c0 = lg[i]; f0 = i; }
        int f1 = -1; float c1 = -1e30f;
#pragma unroll
        for (int i = 0; i < 8; ++i) if (i != f0 && lg[i] > c1) { c1 = lg[i]; f1 = i; }
        float wb1 = __expf(c1 - c0), sb = 1.f + wb1;
        float wb0s = 2.f / sb, wb1s = 2.f * wb1 / sb;   // SCALING=2 folded in
#pragma unroll
        for (int e = 0; e < 8; ++e)
            sCb[t][e] = (e == f0) ? wb0s : (e == f1) ? wb1s : 0.f;
    }
    __syncthreads();

    if (tx < 256) {
        const int t = tx >> 4, gg = tx & 15;
        const float w0 = sW0[t], w1 = sW1[t];
        const int e0 = sE0[t], e1 = sE1[t];
        const float cb = sCb[t][gg >> 1];
        h4 o;
#pragma unroll
        for (int j = 0; j < 4; ++j) {
            int r = (gg * 4 + j) & 7;
            float mid = w0 * (pLp[t * 66 + e0 * 8 + r] + pLp[1056 + t * 66 + e0 * 8 + r])
                      + w1 * (pLp[t * 66 + e1 * 8 + r] + pLp[1056 + t * 66 + e1 * 8 + r]);
            o[j] = (_Float16)(cb * mid);
        }
        *(h4*)(MbLp + ((gg >> 1) * 16 + t) * 8 + (gg & 1) * 4) = o;
    }
    __syncthreads();

    // ================= phase 3: out[16x4096] = Mb[16x64] @ WbF ===============
    // Barrier-free. A-frags in regs; B planes are wave-private -> per-lane
    // register loads from L2-resident WbB (plane ks*8+w, lane l*16).
    // Depth-2 register ping-pong (16 VGPR buffers).
    h8 a30 = *(const h8*)(MbLp + ((0 * 4 + kf) * 16 + mr) * 8);
    h8 a31 = *(const h8*)(MbLp + ((1 * 4 + kf) * 16 + mr) * 8);
    const uint4* wb4 = (const uint4*)WbB;       // chunk = 1024 uint4
    float* outp = out + (size_t)(m0 + kf * 4) * D_OUT;

    uint4 C0[2], C1[2];
#define LDB3(Cd, CH) do {                                                      \
    Cd[0] = wb4[(size_t)(CH) * 1024 + w * 64 + l];                             \
    Cd[1] = wb4[(size_t)(CH) * 1024 + 512 + w * 64 + l];                       \
  } while (0)

#define CMP3(Cs, CH) do {                                                      \
    f4v o0 = (f4v){0.f,0.f,0.f,0.f};                                           \
    o0 = __builtin_amdgcn_mfma_f32_16x16x32_f16(a30, as_h8(Cs[0]), o0, 0,0,0); \
    o0 = __builtin_amdgcn_mfma_f32_16x16x32_f16(a31, as_h8(Cs[1]), o0, 0,0,0); \
    int n0_ = (CH) * 128 + w * 16 + mr;                                        \
    _Pragma("unroll") for (int r_ = 0; r_ < 4; ++r_)                           \
        outp[(size_t)r_ * D_OUT + n0_] = o0[r_];                               \
  } while (0)

    LDB3(C0, 0);
#pragma unroll 1
    for (int c = 0; c < 30; c += 2) {
        LDB3(C1, c + 1); CMP3(C0, c);
        LDB3(C0, c + 2); CMP3(C1, c + 1);
    }
    LDB3(C1, 31); CMP3(C0, 30); CMP3(C1, 31);
#undef LDB3
#undef CMP3

    // ================= aux_final (block 0 only) ==============================
    if (blockIdx.x == 0) {
        if (tx < 16) {
            double s = 0.0;
#pragma unroll
            for (int b = 0; b < 32; ++b) s += pax[b * 16 + tx];
            sl[tx] = s;
        }
        __syncthreads();
        if (tx == 0) {
            double pa[8], pb[8], ma = 0.0, mb = 0.0;
            for (int e = 0; e < 8; ++e) { pa[e] = sl[e] / 8192.0;     ma += pa[e] / 8.0; }
            for (int e = 0; e < 8; ++e) { pb[e] = sl[8 + e] / 8192.0; mb += pb[e] / 8.0; }
            double va = 0.0, vb = 0.0;
            for (int e = 0; e < 8; ++e) { double d = pa[e] - ma; va += d * d; }
            for (int e = 0; e < 8; ++e) { double d = pb[e] - mb; vb += d * d; }
            out[(size_t)T_TOK * D_OUT + 0] = (float)(8.0 * va / 7.0);
            out[(size_t)T_TOK * D_OUT + 1] = (float)(8.0 * vb / 7.0);
        }
    }
}

extern "C" void kernel_launch(void* const* d_in, const int* in_sizes, int n_in,
                              void* d_out, int out_size, void* d_ws, size_t ws_size,
                              hipStream_t stream) {
    const float* x  = (const float*)d_in[0];
    const float* la = (const float*)d_in[1];
    const float* lb = (const float*)d_in[2];
    const float* Wa = (const float*)d_in[3];
    const float* Wb = (const float*)d_in[4];
    float* out = (float*)d_out;

    char* ws = (char*)d_ws;
    _Float16* WaB = (_Float16*)ws;                 // 512 KB
    _Float16* WbB = (_Float16*)(ws + 524288);      // 512 KB
    double*   pax = (double*)(ws + 1048576);       // 4 KB

    prep<<<416, 256, 0, stream>>>(Wa, Wb, la, lb, WaB, WbB, pax);
    fused<<<512, 512, 0, stream>>>(x, WaB, WbB, la, lb, out, pax);
}

// Round 6
// 268.494 us; speedup vs baseline: 1.0362x; 1.0094x over previous
//
#include <hip/hip_runtime.h>

#define T_TOK 8192
#define D_IN  4096
#define D_OUT 4096

typedef _Float16 h2 __attribute__((ext_vector_type(2)));
typedef _Float16 h4 __attribute__((ext_vector_type(4)));
typedef _Float16 h8 __attribute__((ext_vector_type(8)));
typedef float    f4v __attribute__((ext_vector_type(4)));

__device__ __forceinline__ h2 pkrtz(float a, float b) {
    auto r = __builtin_amdgcn_cvt_pkrtz(a, b);
    h2 o; __builtin_memcpy(&o, &r, 4); return o;
}
__device__ __forceinline__ h8 cvt8(float4 f0, float4 f1) {
    h2 p0 = pkrtz(f0.x, f0.y), p1 = pkrtz(f0.z, f0.w);
    h2 p2 = pkrtz(f1.x, f1.y), p3 = pkrtz(f1.z, f1.w);
    return (h8){p0.x, p0.y, p1.x, p1.y, p2.x, p2.y, p3.x, p3.y};
}
__device__ __forceinline__ h8 as_h8(uint4 u) { h8 b; __builtin_memcpy(&b, &u, 16); return b; }

// async 16B global->LDS (hardware DMA: wave-uniform LDS base + lane*16)
__device__ __forceinline__ void gl_lds16(const void* g, void* l) {
    __builtin_amdgcn_global_load_lds(
        (const __attribute__((address_space(1))) unsigned int*)g,
        (__attribute__((address_space(3))) unsigned int*)l, 16, 0, 0);
}

// MFMA 16x16x32 f16 layouts (verified m89/m91/m120):
//   A-frag: lane holds A[m=lane&15][k=(lane>>4)*8+j], j=0..7 (one 16B h8)
//   B-frag: lane holds B[k=(lane>>4)*8+j][n=lane&15]
//   C/D:    row=(lane>>4)*4+reg, col=lane&15
// Weight tiles stored as 1024B "planes": lane l's h8 at plane+l*16 ->
// wave-wide b128 access is contiguous 1024B (zero bank conflicts).

// ---- prep: Wa->WaB planes (bid<256), Wb->WbB planes (bid<384), aux ----------
__global__ __launch_bounds__(256)
void prep(const float* __restrict__ Wa, const float* __restrict__ Wb,
          const float* __restrict__ la, const float* __restrict__ lb,
          _Float16* __restrict__ WaB, _Float16* __restrict__ WbB,
          double* __restrict__ pax) {
    const int bid = blockIdx.x, tx = threadIdx.x;
    __shared__ double red[4][16];
    if (bid < 256) {
        // Wa [er=64][k=4096] f32 -> chunk it=k>>7, plane p=ks*4+g, lane kf*16+mr
        int gid = bid * 256 + tx;                // 0..65535
        int er = gid >> 10, k0 = (gid & 1023) * 4;
        float4 v = ((const float4*)Wa)[gid];
        h2 p0 = pkrtz(v.x, v.y), p1 = pkrtz(v.z, v.w);
        h4 o = { p0.x, p0.y, p1.x, p1.y };
        int it = k0 >> 7, ks = (k0 >> 5) & 3, kf = (k0 >> 3) & 3;
        int g = er >> 4, mr = er & 15;
        *(h4*)(WaB + it * 8192 + (ks * 4 + g) * 512 + (kf * 16 + mr) * 8
               + (k0 & 7)) = o;
    } else if (bid < 384) {
        // Wb [e][o][r] f32, k=e*8+r, n=o -> chunk ch=o>>7, plane p=(e>>2)*8+wv,
        // lane (e&3)*16+mr (wv=(o>>4)&7, mr=o&15), byte j=r.
        int gid = (bid - 256) * 256 + tx;        // 0..32767
        int e = gid >> 12, o = gid & 4095;
        const float4* p = (const float4*)(Wb + ((size_t)e * 4096 + o) * 8);
        h8 v = cvt8(p[0], p[1]);
        int ch = o >> 7, wv = (o >> 4) & 7, mr = o & 15;
        *(h8*)(WbB + (size_t)ch * 8192 + ((e >> 2) * 8 + wv) * 512
               + ((e & 3) * 16 + mr) * 8) = v;
    } else {
        // aux_partial: 32 blocks, per-token full softmax partial sums (f64)
        const int ab = bid - 384;
        const int t = ab * 256 + tx;
        double loc[16];
        {
            float l[8];
#pragma unroll
            for (int i = 0; i < 8; ++i) l[i] = la[(size_t)t * 8 + i];
            float m = l[0];
#pragma unroll
            for (int i = 1; i < 8; ++i) m = fmaxf(m, l[i]);
            float s = 0.f, e[8];
#pragma unroll
            for (int i = 0; i < 8; ++i) { e[i] = __expf(l[i] - m); s += e[i]; }
#pragma unroll
            for (int i = 0; i < 8; ++i) loc[i] = (double)(e[i] / s);
        }
        {
            float l[8];
#pragma unroll
            for (int i = 0; i < 8; ++i) l[i] = lb[(size_t)t * 8 + i];
            float m = l[0];
#pragma unroll
            for (int i = 1; i < 8; ++i) m = fmaxf(m, l[i]);
            float s = 0.f, e[8];
#pragma unroll
            for (int i = 0; i < 8; ++i) { e[i] = __expf(l[i] - m); s += e[i]; }
#pragma unroll
            for (int i = 0; i < 8; ++i) loc[8 + i] = (double)(e[i] / s);
        }
        const int lane = tx & 63, wid = tx >> 6;
#pragma unroll
        for (int v = 0; v < 16; ++v) {
            double s = loc[v];
#pragma unroll
            for (int off = 32; off > 0; off >>= 1) s += __shfl_down(s, off, 64);
            if (lane == 0) red[wid][v] = s;
        }
        __syncthreads();
        if (tx < 16)
            pax[ab * 16 + tx] = red[0][tx] + red[1][tx] + red[2][tx] + red[3][tx];
    }
}

// ---- g1: part[t][y][er] = x[t][K-half y] @ WaT ------------------------------
// grid (512 token-tiles, 2 K-halves) x 512 thr. r5's verified counted-vmcnt
// 3-buffer global_load_lds pipeline, 16 iters. Pure-read streaming kernel.
__global__ __launch_bounds__(512, 4)
void g1(const float* __restrict__ x, const _Float16* __restrict__ WaB,
        float* __restrict__ part) {
    __shared__ char S[73728];          // 3 x 24KB (x 8KB @+0, Wa 16KB @+8192)
    const int tx = threadIdx.x, l = tx & 63, w = tx >> 6;
    const int mr = l & 15, kf = l >> 4;
    const int m0 = blockIdx.x * 16;
    const int y  = blockIdx.y;         // K-half: k in [y*2048, y*2048+2048)
    const int g = w & 3, kh = w >> 2;  // er-group / sub-K-half
    const int er1 = g * 16 + mr;

    f4v acc = (f4v){0.f, 0.f, 0.f, 0.f};

    // 24 planes/iter (8 x + 16 wa), 3 DMAs per wave -> exact vmcnt counting.
#define STAGE1(IT, BUF) do {                                                   \
    _Pragma("unroll") for (int i_ = 0; i_ < 3; ++i_) {                         \
        int p_ = w * 3 + i_;                                                   \
        if (p_ < 8) {                                                          \
            const char* src_ = (const char*)x + (size_t)(m0 + mr) * 16384      \
                + (size_t)y * 8192 + (size_t)(IT) * 512                        \
                + (p_ >> 1) * 128 + kf * 32 + (p_ & 1) * 16;                   \
            gl_lds16(src_, S + (BUF) * 24576 + p_ * 1024);                     \
        } else {                                                               \
            int q_ = p_ - 8;                                                   \
            const char* src_ = (const char*)WaB                                \
                + ((size_t)y * 16 + (IT)) * 16384 + q_ * 1024 + l * 16;        \
            gl_lds16(src_, S + (BUF) * 24576 + 8192 + q_ * 1024);              \
        }                                                                      \
    }                                                                          \
  } while (0)

#define CMP1(BUF) do {                                                         \
    _Pragma("unroll") for (int i_ = 0; i_ < 2; ++i_) {                         \
        int ks_ = kh * 2 + i_;                                                 \
        float4 f0_ = *(const float4*)(S + (BUF) * 24576 + (ks_ * 2) * 1024 + l * 16);     \
        float4 f1_ = *(const float4*)(S + (BUF) * 24576 + (ks_ * 2 + 1) * 1024 + l * 16); \
        h8 a_ = cvt8(f0_, f1_);                                                \
        h8 b_ = *(const h8*)(S + (BUF) * 24576 + 8192                          \
                             + (ks_ * 4 + g) * 1024 + l * 16);                 \
        acc = __builtin_amdgcn_mfma_f32_16x16x32_f16(a_, b_, acc, 0, 0, 0);    \
    }                                                                          \
  } while (0)

    STAGE1(0, 0);
    STAGE1(1, 1);
    {
        int bc = 0;                    // buffer of iter it  (it % 3)
        int bs = 2;                    // buffer of iter it+2
#pragma unroll 1
        for (int it = 0; it < 15; ++it) {
            asm volatile("s_waitcnt vmcnt(3)" ::: "memory");  // iter-it DMAs done
            __builtin_amdgcn_s_barrier();                     // raw: no drain
            if (it < 14) STAGE1(it + 2, bs);
            CMP1(bc);
            bc = (bc == 2) ? 0 : bc + 1;
            bs = (bs == 2) ? 0 : bs + 1;
        }
        asm volatile("s_waitcnt vmcnt(0)" ::: "memory");      // last iter drain
        __builtin_amdgcn_s_barrier();
        CMP1(0);                                              // iter 15, 15%3==0
    }
#undef STAGE1
#undef CMP1

    // sub-half reduction in LDS (overlay buf1: [24576,49152), dead since it=14)
    float* pLp = (float*)(S + 24576);  // [kh][16][66]
#pragma unroll
    for (int r = 0; r < 4; ++r) pLp[kh * 1056 + (kf * 4 + r) * 66 + er1] = acc[r];
    __syncthreads();
#pragma unroll
    for (int rep = 0; rep < 2; ++rep) {
        int idx = rep * 512 + tx;      // 0..1023 = (t, er)
        int t = idx >> 6, er = idx & 63;
        part[((size_t)(m0 + t) * 2 + y) * 64 + er]
            = pLp[t * 66 + er] + pLp[1056 + t * 66 + er];
    }
}

// ---- g2: combine + routing + out[32x512 tile] = Mb @ WbF --------------------
// 2048 blocks x 256 thr (4 waves): tb=bid>>3 token-tile (32 tok), cs=bid&7
// col-slice (512 cols). No K-loop; barrier-free depth-2 col pipeline.
__global__ __launch_bounds__(256)
void g2(const float* __restrict__ part, const _Float16* __restrict__ WbB,
        const float* __restrict__ la, const float* __restrict__ lb,
        float* __restrict__ out, const double* __restrict__ pax) {
    __shared__ float    Ssum[32][68];  // K-split-summed part (f4-aligned rows)
    __shared__ _Float16 MbL[32 * 72];  // Mb[t][er], row pad 72 (16B-aligned)
    __shared__ float sW0[32], sW1[32], sCb[32][8];
    __shared__ int   sE0[32], sE1[32];
    __shared__ double sl[16];

    const int tx = threadIdx.x, l = tx & 63, w = tx >> 6;
    const int mr = l & 15, kf = l >> 4;
    const int bid = blockIdx.x;
    const int tb = bid >> 3, cs = bid & 7;
    const int t0 = tb * 32;

    // ---- stage summed part (part[t][2][64] f32 = 32 float4/token) ----
    {
        const float4* P4 = (const float4*)part;
#pragma unroll
        for (int rep = 0; rep < 2; ++rep) {
            int idx = rep * 256 + tx;          // 0..511 = (t, q)
            int t = idx >> 4, q = idx & 15;
            float4 a = P4[(size_t)(t0 + t) * 32 + q];
            float4 b = P4[(size_t)(t0 + t) * 32 + 16 + q];
            float4 s = { a.x + b.x, a.y + b.y, a.z + b.z, a.w + b.w };
            *(float4*)&Ssum[t][q * 4] = s;
        }
    }
    // ---- routing: thread t handles token t0+t ----
    if (tx < 32) {
        const int t = tx;
        float lg[8];
#pragma unroll
        for (int i = 0; i < 8; ++i) lg[i] = la[(size_t)(t0 + t) * 8 + i];
        int e0 = 0; float b0 = lg[0];
#pragma unroll
        for (int i = 1; i < 8; ++i) if (lg[i] > b0) { b0 = lg[i]; e0 = i; }
        int e1 = -1; float b1 = -1e30f;
#pragma unroll
        for (int i = 0; i < 8; ++i) if (i != e0 && lg[i] > b1) { b1 = lg[i]; e1 = i; }
        float w1 = __expf(b1 - b0), s = 1.f + w1;
        sW0[t] = 1.f / s; sW1[t] = w1 / s; sE0[t] = e0; sE1[t] = e1;

#pragma unroll
        for (int i = 0; i < 8; ++i) lg[i] = lb[(size_t)(t0 + t) * 8 + i];
        int f0 = 0; float c0 = lg[0];
#pragma unroll
        for (int i = 1; i < 8; ++i) if (lg[i] > c0) { c0 = lg[i]; f0 = i; }
        int f1 = -1; float c1 = -1e30f;
#pragma unroll
        for (int i = 0; i < 8; ++i) if (i != f0 && lg[i] > c1) { c1 = lg[i]; f1 = i; }
        float wb1 = __expf(c1 - c0), sb = 1.f + wb1;
        float wb0s = 2.f / sb, wb1s = 2.f * wb1 / sb;   // SCALING=2 folded in
#pragma unroll
        for (int e = 0; e < 8; ++e)
            sCb[t][e] = (e == f0) ? wb0s : (e == f1) ? wb1s : 0.f;
    }
    __syncthreads();

    // ---- Mb[t][er] = coefB[er>>3] * (w0*S[t][e0*8+r] + w1*S[t][e1*8+r]) ----
#pragma unroll
    for (int rep = 0; rep < 8; ++rep) {
        int idx = rep * 256 + tx;              // 0..2047 = (t, er)
        int t = idx >> 6, er = idx & 63;
        float mid = sW0[t] * Ssum[t][sE0[t] * 8 + (er & 7)]
                  + sW1[t] * Ssum[t][sE1[t] * 8 + (er & 7)];
        MbL[t * 72 + er] = (_Float16)(sCb[t][er >> 3] * mid);
    }
    __syncthreads();

    // ---- col loop: wave w owns 128-col chunk ch=cs*4+w (8 16-col groups) ----
    // A-frag: token = mf*16 + mr, k = ks*32 + kf*8 + j  ->  MbL[t*72 + k]
    h8 a00 = *(const h8*)(MbL + (0 * 16 + mr) * 72 + 0 * 32 + kf * 8);
    h8 a01 = *(const h8*)(MbL + (0 * 16 + mr) * 72 + 1 * 32 + kf * 8);
    h8 a10 = *(const h8*)(MbL + (1 * 16 + mr) * 72 + 0 * 32 + kf * 8);
    h8 a11 = *(const h8*)(MbL + (1 * 16 + mr) * 72 + 1 * 32 + kf * 8);
    const uint4* wb4 = (const uint4*)WbB;
    const int ch = cs * 4 + w;
    const size_t cb = (size_t)ch * 1024;       // chunk = 1024 uint4
    float* outp = out + (size_t)(t0 + kf * 4) * D_OUT;

    uint4 C0[2], C1[2];
#define LDB(Cd, c) do {                                                        \
    Cd[0] = wb4[cb + (size_t)(c) * 64 + l];                                    \
    Cd[1] = wb4[cb + 512 + (size_t)(c) * 64 + l];                              \
  } while (0)

#define CMP(Cs, c) do {                                                        \
    f4v o0 = (f4v){0.f,0.f,0.f,0.f}, o1 = (f4v){0.f,0.f,0.f,0.f};              \
    o0 = __builtin_amdgcn_mfma_f32_16x16x32_f16(a00, as_h8(Cs[0]), o0, 0,0,0); \
    o0 = __builtin_amdgcn_mfma_f32_16x16x32_f16(a01, as_h8(Cs[1]), o0, 0,0,0); \
    o1 = __builtin_amdgcn_mfma_f32_16x16x32_f16(a10, as_h8(Cs[0]), o1, 0,0,0); \
    o1 = __builtin_amdgcn_mfma_f32_16x16x32_f16(a11, as_h8(Cs[1]), o1, 0,0,0); \
    int n0 = ch * 128 + (c) * 16 + mr;                                         \
    _Pragma("unroll") for (int r_ = 0; r_ < 4; ++r_) {                         \
        outp[(size_t)r_ * D_OUT + n0]        = o0[r_];                         \
        outp[(size_t)(16 + r_) * D_OUT + n0] = o1[r_]; }                       \
  } while (0)

    LDB(C0, 0);
#pragma unroll 1
    for (int c = 0; c < 6; c += 2) {
        LDB(C1, c + 1); CMP(C0, c);
        LDB(C0, c + 2); CMP(C1, c + 1);
    }
    LDB(C1, 7); CMP(C0, 6); CMP(C1, 7);
#undef LDB
#undef CMP

    // ---- aux_final (block 0 only) ----
    if (bid == 0) {
        if (tx < 16) {
            double s = 0.0;
#pragma unroll
            for (int b = 0; b < 32; ++b) s += pax[b * 16 + tx];
            sl[tx] = s;
        }
        __syncthreads();
        if (tx == 0) {
            double pa[8], pb[8], ma = 0.0, mb = 0.0;
            for (int e = 0; e < 8; ++e) { pa[e] = sl[e] / 8192.0;     ma += pa[e] / 8.0; }
            for (int e = 0; e < 8; ++e) { pb[e] = sl[8 + e] / 8192.0; mb += pb[e] / 8.0; }
            double va = 0.0, vb = 0.0;
            for (int e = 0; e < 8; ++e) { double d = pa[e] - ma; va += d * d; }
            for (int e = 0; e < 8; ++e) { double d = pb[e] - mb; vb += d * d; }
            out[(size_t)T_TOK * D_OUT + 0] = (float)(8.0 * va / 7.0);
            out[(size_t)T_TOK * D_OUT + 1] = (float)(8.0 * vb / 7.0);
        }
    }
}

extern "C" void kernel_launch(void* const* d_in, const int* in_sizes, int n_in,
                              void* d_out, int out_size, void* d_ws, size_t ws_size,
                              hipStream_t stream) {
    const float* x  = (const float*)d_in[0];
    const float* la = (const float*)d_in[1];
    const float* lb = (const float*)d_in[2];
    const float* Wa = (const float*)d_in[3];
    const float* Wb = (const float*)d_in[4];
    float* out = (float*)d_out;

    char* ws = (char*)d_ws;
    _Float16* WaB  = (_Float16*)ws;                // 512 KB
    _Float16* WbB  = (_Float16*)(ws + 524288);     // 512 KB
    double*   pax  = (double*)(ws + 1048576);      // 4 KB
    float*    partb = (float*)(ws + 1052672);      // 4 MB  part[t][2][64] f32

    prep<<<416, 256, 0, stream>>>(Wa, Wb, la, lb, WaB, WbB, pax);
    g1<<<dim3(512, 2), 512, 0, stream>>>(x, WaB, partb);
    g2<<<2048, 256, 0, stream>>>(partb, WbB, la, lb, out, pax);
}